// Round 1
// baseline (425.764 us; speedup 1.0000x reference)
//
#include <hip/hip_runtime.h>

// modConv: y = demod(b,fo) * conv3x3(x * s(b,fi), w * w_scale)
// Strategy: bf16 MFMA implicit GEMM (M=fo, N=pixels, K=fi, 9 taps accumulated).
// Prep kernels build s, demod d, NHWC bf16 modulated x, tap-major bf16 w.

typedef __bf16 bf16_t;
typedef __bf16 bf16x8 __attribute__((ext_vector_type(8)));
typedef float floatx4 __attribute__((ext_vector_type(4)));

#define FI_ 512
#define FO_ 512
#define NB_ 8
#define H_ 64
#define W_ 64
#define HW_ 4096
#define FCSCALE 0.04419417382415922f   /* 512^-0.5 */
#define WSCALE  0.014731391274719742f  /* (512*9)^-0.5 */

__device__ __forceinline__ void gload_lds16(const bf16_t* g, bf16_t* l) {
  // async 16B-per-lane global->LDS; LDS dest = wave-uniform base + lane*16
  __builtin_amdgcn_global_load_lds(
      (const __attribute__((address_space(1))) void*)g,
      (__attribute__((address_space(3))) void*)l, 16, 0, 0);
}

// s[b][fi] = fc_scale * sum_d style[b][d]*fc_w[fi][d] + fc_b[fi]
__global__ void k_style(const float* __restrict__ style, const float* __restrict__ fc_w,
                        const float* __restrict__ fc_b, float* __restrict__ s_out) {
  int t = blockIdx.x * 256 + threadIdx.x;       // 0..4095
  int b = t >> 9, fi = t & 511;
  const float* st = style + b * 512;
  const float* fw = fc_w + (size_t)fi * 512;
  float acc = 0.f;
  for (int d = 0; d < 512; d += 4)
    acc += st[d] * fw[d] + st[d + 1] * fw[d + 1] + st[d + 2] * fw[d + 2] + st[d + 3] * fw[d + 3];
  s_out[t] = acc * FCSCALE + fc_b[fi];
}

// wsq[fo][fi] = sum_tap (w*ws)^2 ; wt[tap][fo][fi] = bf16(w*ws)
__global__ void k_wsq_wt(const float* __restrict__ w, float* __restrict__ wsq,
                         bf16_t* __restrict__ wt) {
  int idx = blockIdx.x * 256 + threadIdx.x;     // fo*512+fi, 262144 total
  const float* wp = w + (size_t)idx * 9;
  float v[9], q = 0.f;
#pragma unroll
  for (int k = 0; k < 9; ++k) { v[k] = wp[k] * WSCALE; q += v[k] * v[k]; }
  wsq[idx] = q;
#pragma unroll
  for (int k = 0; k < 9; ++k) wt[(size_t)k * 262144 + idx] = (bf16_t)v[k];
}

// d[b][fo] = rsqrt(sum_fi wsq[fo][fi]*s[b][fi]^2 + eps)
__global__ void k_demod(const float* __restrict__ wsq, const float* __restrict__ s,
                        float* __restrict__ dcoef) {
  int t = blockIdx.x * 256 + threadIdx.x;       // 0..4095
  int b = t >> 9, fo = t & 511;
  const float* wq = wsq + (size_t)fo * 512;
  const float* sp = s + b * 512;
  float acc = 0.f;
  for (int fi = 0; fi < 512; ++fi) { float sv = sp[fi]; acc += wq[fi] * sv * sv; }
  dcoef[t] = rsqrtf(acc + 1e-8f);
}

// xT[b][h][w][fi] = bf16(x[b][fi][h][w] * s[b][fi])   (NCHW fp32 -> NHWC bf16, LDS transpose)
__global__ void k_modx(const float* __restrict__ x, const float* __restrict__ s,
                       bf16_t* __restrict__ xT) {
  __shared__ float tile[32][65];                // +1 pad: conflict-free transpose
  int b = blockIdx.z;
  int fi0 = blockIdx.x * 32;
  int hw0 = blockIdx.y * 64;
  int t = threadIdx.x;
  int tx = t & 63, ty = t >> 6;                 // read: 64-wide coalesced rows
#pragma unroll
  for (int i = 0; i < 8; ++i) {
    int fi_l = i * 4 + ty;                      // 0..31
    float sv = s[b * 512 + fi0 + fi_l];
    tile[fi_l][tx] = x[((size_t)(b * 512 + fi0 + fi_l)) * HW_ + hw0 + tx] * sv;
  }
  __syncthreads();
  int kx = t & 31, ky = t >> 5;                 // write: 32 fi * 2B = 64B coalesced
#pragma unroll
  for (int j = 0; j < 8; ++j) {
    int hw_l = j * 8 + ky;
    xT[((size_t)(b * HW_ + hw0 + hw_l)) * 512 + fi0 + kx] = (bf16_t)tile[kx][hw_l];
  }
}

// Main: block = 128 fo x 256 px (4 rows), 4 waves each 128 fo x 64 px (1 row).
// K loop: 9 taps x 16 fi-chunks of 32. LDS K-granule-major: slot = c*NPX + px.
__global__ __launch_bounds__(256, 2) void k_conv(const bf16_t* __restrict__ wt,
                                                 const bf16_t* __restrict__ xT,
                                                 const float* __restrict__ dcoef,
                                                 const bf16_t* __restrict__ zerobuf,
                                                 float* __restrict__ out) {
  __shared__ __align__(16) bf16_t xls[4 * 256 * 8];   // 16 KB: [c 0..3][px 0..255][8 bf16]
  __shared__ __align__(16) bf16_t wls[4 * 128 * 8];   //  8 KB: [c 0..3][fo 0..127][8 bf16]

  int foB = blockIdx.x;                 // 0..3
  int hq  = blockIdx.y;                 // 0..15  -> rows h0..h0+3
  int b   = blockIdx.z;                 // 0..7
  int t = threadIdx.x;
  int wv = t >> 6, lane = t & 63, quad = lane >> 4, l16 = lane & 15;
  int h0 = hq * 4;
  int col = lane;                       // staging px = t: row r == wv, col == lane
  int fo_l = t & 127, chunk_hi = t >> 7;

  floatx4 acc[8][4];
#pragma unroll
  for (int i = 0; i < 8; ++i)
#pragma unroll
    for (int j = 0; j < 4; ++j) acc[i][j] = (floatx4){0.f, 0.f, 0.f, 0.f};

  for (int tap = 0; tap < 9; ++tap) {
    int kh = tap / 3, kw = tap - kh * 3;            // uniform scalar math
    int rg = h0 + wv + kh - 1;                      // wave-uniform source row
    int cg = col + kw - 1;                          // per-lane source col
    bool valid = ((unsigned)rg < 64u) && ((unsigned)cg < 64u);
    const bf16_t* xsrc0 = valid
        ? xT + ((size_t)((b * 64 + rg) * 64 + cg)) * 512
        : zerobuf;
    const bf16_t* wbase = wt + ((size_t)(tap * 512 + foB * 128)) * 512;

    for (int fi0 = 0; fi0 < 512; fi0 += 32) {
      __syncthreads();                              // protect LDS from prior reads
      // stage weights: 512 granules of 16B (2 issues/thread)
#pragma unroll
      for (int itw = 0; itw < 2; ++itw) {
        int cw = itw * 2 + chunk_hi;                // fi granule 0..3
        gload_lds16(wbase + (size_t)fo_l * 512 + fi0 + cw * 8,
                    &wls[(itw * 256 + wv * 64) * 8]);
      }
      // stage x: 1024 granules of 16B (4 issues/thread); OOB lanes -> zerobuf
#pragma unroll
      for (int it = 0; it < 4; ++it) {
        const bf16_t* src = valid ? (xsrc0 + fi0 + it * 8) : zerobuf;
        gload_lds16(src, &xls[(it * 256 + wv * 64) * 8]);
      }
      __syncthreads();                              // drains vmcnt (m97 pattern)

      bf16x8 bfr[4];
#pragma unroll
      for (int j = 0; j < 4; ++j)
        bfr[j] = *(const bf16x8*)&xls[(quad * 256 + wv * 64 + j * 16 + l16) * 8];
#pragma unroll
      for (int i = 0; i < 8; ++i) {
        bf16x8 afr = *(const bf16x8*)&wls[(quad * 128 + i * 16 + l16) * 8];
#pragma unroll
        for (int j = 0; j < 4; ++j)
          acc[i][j] = __builtin_amdgcn_mfma_f32_16x16x32_bf16(afr, bfr[j], acc[i][j], 0, 0, 0);
      }
    }
  }

  // epilogue: C/D layout col = lane&15 (n), row = quad*4 + reg (m); scale by demod
  int h = h0 + wv;
#pragma unroll
  for (int i = 0; i < 8; ++i) {
#pragma unroll
    for (int rr = 0; rr < 4; ++rr) {
      int fo_g = foB * 128 + i * 16 + quad * 4 + rr;
      float dm = dcoef[b * 512 + fo_g];
      float* op = out + ((size_t)((b * 512 + fo_g) * 64 + h)) * 64;
#pragma unroll
      for (int j = 0; j < 4; ++j)
        op[j * 16 + l16] = acc[i][j][rr] * dm;
    }
  }
}

extern "C" void kernel_launch(void* const* d_in, const int* in_sizes, int n_in,
                              void* d_out, int out_size, void* d_ws, size_t ws_size,
                              hipStream_t stream) {
  const float* x     = (const float*)d_in[0];
  const float* style = (const float*)d_in[1];
  const float* w     = (const float*)d_in[2];
  const float* fc_w  = (const float*)d_in[3];
  const float* fc_b  = (const float*)d_in[4];
  float* out = (float*)d_out;
  char* ws = (char*)d_ws;

  // workspace layout (bytes, 256-aligned): total ~37.6 MB
  float*  s       = (float*)(ws);                  // 16 KB
  float*  dcoef   = (float*)(ws + 16384);          // 16 KB
  float*  wsq     = (float*)(ws + 32768);          // 1 MB
  bf16_t* zerobuf = (bf16_t*)(ws + 1081344);       // 256 B of zeros
  bf16_t* wt      = (bf16_t*)(ws + 1081600);       // 4.5 MB  [tap][fo][fi]
  bf16_t* xT      = (bf16_t*)(ws + 5800192);       // 32 MB   [b][h][w][fi]

  hipMemsetAsync(zerobuf, 0, 256, stream);
  k_style<<<16, 256, 0, stream>>>(style, fc_w, fc_b, s);
  k_wsq_wt<<<1024, 256, 0, stream>>>(w, wsq, wt);
  k_demod<<<16, 256, 0, stream>>>(wsq, s, dcoef);
  k_modx<<<dim3(16, 64, 8), 256, 0, stream>>>(x, s, xT);
  k_conv<<<dim3(4, 16, 8), 256, 0, stream>>>(wt, xT, dcoef, zerobuf, out);
}

// Round 2
// 401.931 us; speedup vs baseline: 1.0593x; 1.0593x over previous
//
#include <hip/hip_runtime.h>

// modConv: y = demod(b,fo) * conv3x3(x * s(b,fi), w * w_scale)
// bf16 MFMA implicit GEMM (M=fo, N=pixels, K=fi, 9 taps accumulated).
// R2: XCD=b grid swizzle (grid.x=8 -> lid%8=b -> per-XCD 4MB x slice L2-resident)
//     + double-buffered LDS prefetch (issue it+1 AFTER barrier, compute it).

typedef __bf16 bf16_t;
typedef __bf16 bf16x8 __attribute__((ext_vector_type(8)));
typedef float floatx4 __attribute__((ext_vector_type(4)));

#define HW_ 4096
#define FCSCALE 0.04419417382415922f   /* 512^-0.5 */
#define WSCALE  0.014731391274719742f  /* (512*9)^-0.5 */

__device__ __forceinline__ void gload_lds16(const bf16_t* g, bf16_t* l) {
  __builtin_amdgcn_global_load_lds(
      (const __attribute__((address_space(1))) void*)g,
      (__attribute__((address_space(3))) void*)l, 16, 0, 0);
}

// s[b][fi] = fc_scale * sum_d style[b][d]*fc_w[fi][d] + fc_b[fi]
__global__ void k_style(const float* __restrict__ style, const float* __restrict__ fc_w,
                        const float* __restrict__ fc_b, float* __restrict__ s_out) {
  int t = blockIdx.x * 256 + threadIdx.x;       // 0..4095
  int b = t >> 9, fi = t & 511;
  const float* st = style + b * 512;
  const float* fw = fc_w + (size_t)fi * 512;
  float acc = 0.f;
  for (int d = 0; d < 512; d += 4)
    acc += st[d] * fw[d] + st[d + 1] * fw[d + 1] + st[d + 2] * fw[d + 2] + st[d + 3] * fw[d + 3];
  s_out[t] = acc * FCSCALE + fc_b[fi];
}

// wsq[fo][fi] = sum_tap (w*ws)^2 ; wt[tap][fo][fi] = bf16(w*ws)
__global__ void k_wsq_wt(const float* __restrict__ w, float* __restrict__ wsq,
                         bf16_t* __restrict__ wt) {
  int idx = blockIdx.x * 256 + threadIdx.x;     // fo*512+fi
  const float* wp = w + (size_t)idx * 9;
  float v[9], q = 0.f;
#pragma unroll
  for (int k = 0; k < 9; ++k) { v[k] = wp[k] * WSCALE; q += v[k] * v[k]; }
  wsq[idx] = q;
#pragma unroll
  for (int k = 0; k < 9; ++k) wt[(size_t)k * 262144 + idx] = (bf16_t)v[k];
}

// d[b][fo] = rsqrt(sum_fi wsq[fo][fi]*s[b][fi]^2 + eps)
__global__ void k_demod(const float* __restrict__ wsq, const float* __restrict__ s,
                        float* __restrict__ dcoef) {
  int t = blockIdx.x * 256 + threadIdx.x;
  int b = t >> 9, fo = t & 511;
  const float* wq = wsq + (size_t)fo * 512;
  const float* sp = s + b * 512;
  float acc = 0.f;
  for (int fi = 0; fi < 512; ++fi) { float sv = sp[fi]; acc += wq[fi] * sv * sv; }
  dcoef[t] = rsqrtf(acc + 1e-8f);
}

// xT[b][h][w][fi] = bf16(x[b][fi][h][w] * s[b][fi])
__global__ void k_modx(const float* __restrict__ x, const float* __restrict__ s,
                       bf16_t* __restrict__ xT) {
  __shared__ float tile[32][65];
  int b = blockIdx.z;
  int fi0 = blockIdx.x * 32;
  int hw0 = blockIdx.y * 64;
  int t = threadIdx.x;
  int tx = t & 63, ty = t >> 6;
#pragma unroll
  for (int i = 0; i < 8; ++i) {
    int fi_l = i * 4 + ty;
    float sv = s[b * 512 + fi0 + fi_l];
    tile[fi_l][tx] = x[((size_t)(b * 512 + fi0 + fi_l)) * HW_ + hw0 + tx] * sv;
  }
  __syncthreads();
  int kx = t & 31, ky = t >> 5;
#pragma unroll
  for (int j = 0; j < 8; ++j) {
    int hw_l = j * 8 + ky;
    xT[((size_t)(b * HW_ + hw0 + hw_l)) * 512 + fi0 + kx] = (bf16_t)tile[kx][hw_l];
  }
}

// Main: block = 128 fo x 256 px (4 rows h0..h0+3), 4 waves each 128 fo x 64 px.
// Flattened K loop: 144 its = 9 taps x 16 fi-chunks of 32; double-buffered LDS,
// prefetch(it+1) issued AFTER barrier so its vmcnt drain overlaps compute(it).
__global__ __launch_bounds__(256, 2) void k_conv(const bf16_t* __restrict__ wt,
                                                 const bf16_t* __restrict__ xT,
                                                 const float* __restrict__ dcoef,
                                                 const bf16_t* __restrict__ zerobuf,
                                                 float* __restrict__ out) {
  __shared__ __align__(16) bf16_t xls[2][4 * 256 * 8];   // 2 x 16 KB
  __shared__ __align__(16) bf16_t wls[2][4 * 128 * 8];   // 2 x  8 KB

  int b   = blockIdx.x;                 // 0..7  (grid.x=8 -> linear%8=b -> XCD=b)
  int foB = blockIdx.y;                 // 0..3
  int hq  = blockIdx.z;                 // 0..15 -> rows h0..h0+3
  int t = threadIdx.x;
  int wv = t >> 6, lane = t & 63, quad = lane >> 4, l16 = lane & 15;
  int h0 = hq * 4;
  int fo_l = t & 127, chunk_hi = t >> 7;

  const bf16_t* wtfoB = wt + (size_t)foB * 128 * 512;
  const bf16_t* xTb   = xT + (size_t)b * HW_ * 512;

  floatx4 acc[8][4];
#pragma unroll
  for (int i = 0; i < 8; ++i)
#pragma unroll
    for (int j = 0; j < 4; ++j) acc[i][j] = (floatx4){0.f, 0.f, 0.f, 0.f};

  auto stage = [&](int it, int p) {
    int tap = it >> 4;
    int fi0 = (it & 15) << 5;
    int kh = tap / 3, kw = tap - kh * 3;
    int rg = h0 + wv + kh - 1;          // wave-uniform source row
    int cg = lane + kw - 1;             // per-lane source col
    bool valid = ((unsigned)rg < 64u) && ((unsigned)cg < 64u);
    const bf16_t* xsrc0 = valid ? (xTb + ((size_t)(rg * 64 + cg)) * 512 + fi0)
                                : zerobuf;
    const bf16_t* wbase = wtfoB + (size_t)tap * 512 * 512 + fi0;
    // weights: 512 granules of 16B; granule g = itw*256 + t; fo=g&127, c=g>>7
#pragma unroll
    for (int itw = 0; itw < 2; ++itw) {
      int cw = itw * 2 + chunk_hi;
      gload_lds16(wbase + (size_t)fo_l * 512 + cw * 8,
                  &wls[p][(itw * 256 + wv * 64) * 8]);
    }
    // x: 1024 granules; g = it4*256 + t; px=g&255 (row=wv,col=lane), c=g>>8
#pragma unroll
    for (int it4 = 0; it4 < 4; ++it4) {
      const bf16_t* src = valid ? (xsrc0 + it4 * 8) : zerobuf;
      gload_lds16(src, &xls[p][(it4 * 256 + wv * 64) * 8]);
    }
  };

  stage(0, 0);                          // prologue prefetch

  for (int it = 0; it < 144; ++it) {
    int p = it & 1;
    __syncthreads();                    // drains prefetch(it); protects LDS from
                                        // compute(it-1)'s reads (lgkm drained too)
    if (it + 1 < 144) stage(it + 1, p ^ 1);   // in-flight across compute(it)

    bf16x8 bfr[4];
#pragma unroll
    for (int j = 0; j < 4; ++j)
      bfr[j] = *(const bf16x8*)&xls[p][(quad * 256 + wv * 64 + j * 16 + l16) * 8];
#pragma unroll
    for (int i = 0; i < 8; ++i) {
      bf16x8 afr = *(const bf16x8*)&wls[p][(quad * 128 + i * 16 + l16) * 8];
#pragma unroll
      for (int j = 0; j < 4; ++j)
        acc[i][j] = __builtin_amdgcn_mfma_f32_16x16x32_bf16(afr, bfr[j], acc[i][j], 0, 0, 0);
    }
  }

  // epilogue: C/D layout col=lane&15 (n=px), row=quad*4+reg (m=fo); scale demod
  int h = h0 + wv;
#pragma unroll
  for (int i = 0; i < 8; ++i) {
#pragma unroll
    for (int rr = 0; rr < 4; ++rr) {
      int fo_g = foB * 128 + i * 16 + quad * 4 + rr;
      float dm = dcoef[b * 512 + fo_g];
      float* op = out + ((size_t)((b * 512 + fo_g) * 64 + h)) * 64;
#pragma unroll
      for (int j = 0; j < 4; ++j)
        op[j * 16 + l16] = acc[i][j][rr] * dm;
    }
  }
}

extern "C" void kernel_launch(void* const* d_in, const int* in_sizes, int n_in,
                              void* d_out, int out_size, void* d_ws, size_t ws_size,
                              hipStream_t stream) {
  const float* x     = (const float*)d_in[0];
  const float* style = (const float*)d_in[1];
  const float* w     = (const float*)d_in[2];
  const float* fc_w  = (const float*)d_in[3];
  const float* fc_b  = (const float*)d_in[4];
  float* out = (float*)d_out;
  char* ws = (char*)d_ws;

  float*  s       = (float*)(ws);                  // 16 KB
  float*  dcoef   = (float*)(ws + 16384);          // 16 KB
  float*  wsq     = (float*)(ws + 32768);          // 1 MB
  bf16_t* zerobuf = (bf16_t*)(ws + 1081344);       // 256 B of zeros
  bf16_t* wt      = (bf16_t*)(ws + 1081600);       // 4.5 MB  [tap][fo][fi]
  bf16_t* xT      = (bf16_t*)(ws + 5800192);       // 32 MB   [b][h][w][fi]

  hipMemsetAsync(zerobuf, 0, 256, stream);
  k_style<<<16, 256, 0, stream>>>(style, fc_w, fc_b, s);
  k_wsq_wt<<<1024, 256, 0, stream>>>(w, wsq, wt);
  k_demod<<<16, 256, 0, stream>>>(wsq, s, dcoef);
  k_modx<<<dim3(16, 64, 8), 256, 0, stream>>>(x, s, xT);
  // grid.x = b so linear block id % 8 == b -> XCD-pinned batch slice (L2 locality)
  k_conv<<<dim3(8, 4, 16), 256, 0, stream>>>(wt, xT, dcoef, zerobuf, out);
}